// Round 1
// baseline (2202.616 us; speedup 1.0000x reference)
//
#include <hip/hip_runtime.h>
#include <cstddef>

// ============================================================================
// MultiWaveletTransform — algebraic refactor.
//
// Let D = 32768-pt ortho DCT-II (axis 0 of x.reshape(-1,512)), F = 512-pt.
// T = D X F^T.  Branches:
//   out1 = X M1 + v1 c1^T,             M1 = F^T W1^T F,  v1 = D^T 1
//   out2 = D^T P2 (D X) M2 + w2 c2^T,  M2 = F^T emb(W2^T) F, P2: k%64<32
//   out3 = D^T P3 (D X) M3 + w3 c3^T,  M3 = F^T emb(W3^T) F, P3: k%64<16
// Masked big DCT factorizes via k=64t+j, n=1024u+v:
//   cos(k th_n) = cosA cos(j th_n) - sinA sin(j th_n), A = pi t(2v+1)/1024
// -> modulation over j + u-sum (32 terms), v-fold (v<->1023-v), then shared
//    512x512 C/S GEMMs. v1,w2,w3 via closed-form Dirichlet sums (fp64).
// Workspace: ~168 MB fp32.
// ============================================================================

#define PI_D 3.14159265358979323846

#define BM 64
#define BN 64
#define BK 16
#define LDP 68   // BM+4 pad, keeps float4 alignment (68*4 % 16 == 0)

// ---------------- fill kernels ----------------
__global__ void fill_F_k(float* __restrict__ F) {
  int idx = blockIdx.x * 256 + threadIdx.x;
  if (idx >= 512 * 512) return;
  int k = idx >> 9, m = idx & 511;
  int a = (k * (2 * m + 1)) & 2047;            // exact angle reduction
  float ang = (float)(a * (PI_D / 1024.0));
  float s = (k == 0) ? 0.04419417382415922f /*sqrt(1/512)*/ : 0.0625f /*sqrt(2/512)*/;
  F[idx] = s * cosf(ang);
}

__global__ void fill_CS_k(float* __restrict__ C, float* __restrict__ S) {
  int idx = blockIdx.x * 256 + threadIdx.x;
  if (idx >= 512 * 512) return;
  int t = idx >> 9, v = idx & 511;
  int a = (t * (2 * v + 1)) & 2047;
  float ang = (float)(a * (PI_D / 1024.0));
  C[idx] = cosf(ang);
  S[idx] = sinf(ang);
}

__global__ void fill_cjsj_k(float* __restrict__ cj, float* __restrict__ sj) {
  int idx = blockIdx.x * 256 + threadIdx.x;
  if (idx >= 32 * 32768) return;
  int j = idx >> 15, n = idx & 32767;
  int a = (j * (2 * n + 1)) & 131071;          // period of cos(a*pi/65536)
  float ang = (float)(a * (PI_D / 65536.0));
  cj[idx] = cosf(ang);
  sj[idx] = sinf(ang);
}

// v1[n] = sum_k s_k cos(k th), w2/w3 same over masked k, closed forms (fp64).
__global__ void fill_vw_k(float* __restrict__ v1, float* __restrict__ w2,
                          float* __restrict__ w3) {
  int n = blockIdx.x * 256 + threadIdx.x;
  if (n >= 32768) return;
  const double s1 = 0.005524271728019903;      // sqrt(1/32768)
  const double s2 = 0.0078125;                 // sqrt(2/32768)
  double th = (2 * n + 1) * (PI_D / 65536.0);
  double c = cos(th), s = sin(th);
  double Dr = 1.0 - c, Di = -s;
  double dd = Dr * Dr + Di * Di;
  // Nv = 1 - e^{i*32768*th} = 1 - i*(-1)^n
  double Nr = 1.0, Ni = (n & 1) ? 1.0 : -1.0;
  // v1 = s2*Re[Nv/D] + (s1-s2)
  double vre = (Nr * Dr + Ni * Di) / dd;
  v1[n] = (float)(s2 * vre + (s1 - s2));
  // Gt = Nv / (1 - e^{i*64th})
  int m64 = (2 * n + 1) & 2047;
  double a64 = m64 * (PI_D / 1024.0);
  double D64r = 1.0 - cos(a64), D64i = -sin(a64);
  double d64 = D64r * D64r + D64i * D64i;
  double Gr = (Nr * D64r + Ni * D64i) / d64;
  double Gi = (Ni * D64r - Nr * D64i) / d64;
  // S32 = (1 - e^{i*32th})/D
  int m32 = (2 * n + 1) & 4095;
  double a32 = m32 * (PI_D / 2048.0);
  double S32nr = 1.0 - cos(a32), S32ni = -sin(a32);
  double S32r = (S32nr * Dr + S32ni * Di) / dd;
  double S32i = (S32ni * Dr - S32nr * Di) / dd;
  w2[n] = (float)(s2 * (S32r * Gr - S32i * Gi) + (s1 - s2));
  // S16 = (1 - e^{i*16th})/D
  int m16 = (2 * n + 1) & 8191;
  double a16 = m16 * (PI_D / 4096.0);
  double S16nr = 1.0 - cos(a16), S16ni = -sin(a16);
  double S16r = (S16nr * Dr + S16ni * Di) / dd;
  double S16i = (S16ni * Dr - S16nr * Di) / dd;
  w3[n] = (float)(s2 * (S16r * Gr - S16i * Gi) + (s1 - s2));
}

// c[l] = sum_{m<Kd} F[m][l] * b[m]
__global__ void gemv_FT_k(const float* __restrict__ F, const float* __restrict__ b,
                          float* __restrict__ out, int Kd) {
  int l = blockIdx.x * 256 + threadIdx.x;
  if (l >= 512) return;
  float acc = 0.f;
  for (int m = 0; m < Kd; m++) acc += F[m * 512 + l] * b[m];
  out[l] = acc;
}

__global__ void fixup_k0_k(float* __restrict__ Z) {
  int l = threadIdx.x;   // row t=0, j=0 cols -> first 512 floats; s_0^2 = 1/N not 2/N
  if (l < 512) Z[l] *= 0.5f;
}

// ---------------- GEMMs (fp32, 64x64 tile, 16x16 threads, 4x4 micro) --------
// C[M,N] = A[M,K] @ B[K,N]; optional row-remap on A: phys=((r>>sb)<<tb)|(r&((1<<sb)-1))
// optional rank-1 epilogue + u[r]*w[c]; custom ldc/col-offset for banded output.
__global__ __launch_bounds__(256) void gemm_nn_k(
    const float* __restrict__ A, int lda, const float* __restrict__ B, int ldb,
    float* __restrict__ Cm, int ldc, int coff, int Kd,
    const float* __restrict__ u, const float* __restrict__ w, int sb, int tb) {
  __shared__ float As[BK][LDP];
  __shared__ float Bs[BK][LDP];
  int tx = threadIdx.x, ty = threadIdx.y;
  int tid = ty * 16 + tx;
  int m0 = blockIdx.y * BM, n0 = blockIdx.x * BN;
  int mask = (1 << sb) - 1;
  float acc[4][4] = {};
  for (int k0 = 0; k0 < Kd; k0 += BK) {
#pragma unroll
    for (int i = 0; i < 4; i++) {
      int idx = tid + i * 256;
      int kk = idx & 15, m = idx >> 4;
      int r = m0 + m;
      int pr = ((r >> sb) << tb) | (r & mask);
      As[kk][m] = A[(size_t)pr * lda + k0 + kk];
    }
#pragma unroll
    for (int i = 0; i < 4; i++) {
      int idx = tid + i * 256;
      int nn = idx & 63, kk = idx >> 6;
      Bs[kk][nn] = B[(size_t)(k0 + kk) * ldb + n0 + nn];
    }
    __syncthreads();
#pragma unroll
    for (int kk = 0; kk < BK; kk++) {
      float4 a4 = *(const float4*)&As[kk][ty * 4];
      float4 b4 = *(const float4*)&Bs[kk][tx * 4];
      float a[4] = {a4.x, a4.y, a4.z, a4.w};
      float b[4] = {b4.x, b4.y, b4.z, b4.w};
#pragma unroll
      for (int i = 0; i < 4; i++)
#pragma unroll
        for (int jj = 0; jj < 4; jj++) acc[i][jj] += a[i] * b[jj];
    }
    __syncthreads();
  }
#pragma unroll
  for (int i = 0; i < 4; i++) {
    int r = m0 + ty * 4 + i;
#pragma unroll
    for (int jj = 0; jj < 4; jj++) {
      int c = n0 + tx * 4 + jj;
      float val = acc[i][jj];
      if (u) val += u[r] * w[c];
      Cm[(size_t)r * ldc + coff + c] = val;
    }
  }
}

// C[M,N] = A^T @ B, A stored [K,M] (lda), B [K,N] (ldb)
__global__ __launch_bounds__(256) void gemm_tn_k(
    const float* __restrict__ A, int lda, const float* __restrict__ B, int ldb,
    float* __restrict__ Cm, int ldc, int Kd) {
  __shared__ float As[BK][LDP];
  __shared__ float Bs[BK][LDP];
  int tx = threadIdx.x, ty = threadIdx.y;
  int tid = ty * 16 + tx;
  int m0 = blockIdx.y * BM, n0 = blockIdx.x * BN;
  float acc[4][4] = {};
  for (int k0 = 0; k0 < Kd; k0 += BK) {
#pragma unroll
    for (int i = 0; i < 4; i++) {
      int idx = tid + i * 256;
      int m = idx & 63, kk = idx >> 6;
      As[kk][m] = A[(size_t)(k0 + kk) * lda + m0 + m];
    }
#pragma unroll
    for (int i = 0; i < 4; i++) {
      int idx = tid + i * 256;
      int nn = idx & 63, kk = idx >> 6;
      Bs[kk][nn] = B[(size_t)(k0 + kk) * ldb + n0 + nn];
    }
    __syncthreads();
#pragma unroll
    for (int kk = 0; kk < BK; kk++) {
      float4 a4 = *(const float4*)&As[kk][ty * 4];
      float4 b4 = *(const float4*)&Bs[kk][tx * 4];
      float a[4] = {a4.x, a4.y, a4.z, a4.w};
      float b[4] = {b4.x, b4.y, b4.z, b4.w};
#pragma unroll
      for (int i = 0; i < 4; i++)
#pragma unroll
        for (int jj = 0; jj < 4; jj++) acc[i][jj] += a[i] * b[jj];
    }
    __syncthreads();
  }
#pragma unroll
  for (int i = 0; i < 4; i++) {
    int r = m0 + ty * 4 + i;
#pragma unroll
    for (int jj = 0; jj < 4; jj++)
      Cm[(size_t)r * ldc + n0 + tx * 4 + jj] = acc[i][jj];
  }
}

// C = A1@B1 - A2@B2 (all row-major; A [M,K], B [K,N])  -- forward C/S GEMM
__global__ __launch_bounds__(256) void gemm_dual_nn_k(
    const float* __restrict__ A1, const float* __restrict__ A2, int lda,
    const float* __restrict__ B1, const float* __restrict__ B2, int ldb,
    float* __restrict__ Cm, int ldc, int Kd) {
  __shared__ float As1[BK][LDP];
  __shared__ float As2[BK][LDP];
  __shared__ float Bs1[BK][LDP];
  __shared__ float Bs2[BK][LDP];
  int tx = threadIdx.x, ty = threadIdx.y;
  int tid = ty * 16 + tx;
  int m0 = blockIdx.y * BM, n0 = blockIdx.x * BN;
  float acc[4][4] = {};
  for (int k0 = 0; k0 < Kd; k0 += BK) {
#pragma unroll
    for (int i = 0; i < 4; i++) {
      int idx = tid + i * 256;
      int kk = idx & 15, m = idx >> 4;
      As1[kk][m] = A1[(size_t)(m0 + m) * lda + k0 + kk];
      As2[kk][m] = A2[(size_t)(m0 + m) * lda + k0 + kk];
    }
#pragma unroll
    for (int i = 0; i < 4; i++) {
      int idx = tid + i * 256;
      int nn = idx & 63, kk = idx >> 6;
      Bs1[kk][nn] = B1[(size_t)(k0 + kk) * ldb + n0 + nn];
      Bs2[kk][nn] = B2[(size_t)(k0 + kk) * ldb + n0 + nn];
    }
    __syncthreads();
#pragma unroll
    for (int kk = 0; kk < BK; kk++) {
      float4 a4 = *(const float4*)&As1[kk][ty * 4];
      float4 b4 = *(const float4*)&Bs1[kk][tx * 4];
      float4 c4 = *(const float4*)&As2[kk][ty * 4];
      float4 d4 = *(const float4*)&Bs2[kk][tx * 4];
      float a[4] = {a4.x, a4.y, a4.z, a4.w};
      float b[4] = {b4.x, b4.y, b4.z, b4.w};
      float c[4] = {c4.x, c4.y, c4.z, c4.w};
      float d[4] = {d4.x, d4.y, d4.z, d4.w};
#pragma unroll
      for (int i = 0; i < 4; i++)
#pragma unroll
        for (int jj = 0; jj < 4; jj++) acc[i][jj] += a[i] * b[jj] - c[i] * d[jj];
    }
    __syncthreads();
  }
#pragma unroll
  for (int i = 0; i < 4; i++) {
    int r = m0 + ty * 4 + i;
#pragma unroll
    for (int jj = 0; jj < 4; jj++)
      Cm[(size_t)r * ldc + n0 + tx * 4 + jj] = acc[i][jj];
  }
}

// C1 = A1^T@B, C2 = A2^T@B (A stored [K,M]) -- inverse C/S GEMM, shared B loads
__global__ __launch_bounds__(256) void gemm_dual_tn2_k(
    const float* __restrict__ A1, const float* __restrict__ A2, int lda,
    const float* __restrict__ B, int ldb,
    float* __restrict__ C1, float* __restrict__ C2, int ldc, int Kd) {
  __shared__ float As1[BK][LDP];
  __shared__ float As2[BK][LDP];
  __shared__ float Bs[BK][LDP];
  int tx = threadIdx.x, ty = threadIdx.y;
  int tid = ty * 16 + tx;
  int m0 = blockIdx.y * BM, n0 = blockIdx.x * BN;
  float acc1[4][4] = {};
  float acc2[4][4] = {};
  for (int k0 = 0; k0 < Kd; k0 += BK) {
#pragma unroll
    for (int i = 0; i < 4; i++) {
      int idx = tid + i * 256;
      int m = idx & 63, kk = idx >> 6;
      As1[kk][m] = A1[(size_t)(k0 + kk) * lda + m0 + m];
      As2[kk][m] = A2[(size_t)(k0 + kk) * lda + m0 + m];
      Bs[kk][m] = B[(size_t)(k0 + kk) * ldb + n0 + m];
    }
    __syncthreads();
#pragma unroll
    for (int kk = 0; kk < BK; kk++) {
      float4 a4 = *(const float4*)&As1[kk][ty * 4];
      float4 c4 = *(const float4*)&As2[kk][ty * 4];
      float4 b4 = *(const float4*)&Bs[kk][tx * 4];
      float a[4] = {a4.x, a4.y, a4.z, a4.w};
      float c[4] = {c4.x, c4.y, c4.z, c4.w};
      float b[4] = {b4.x, b4.y, b4.z, b4.w};
#pragma unroll
      for (int i = 0; i < 4; i++)
#pragma unroll
        for (int jj = 0; jj < 4; jj++) {
          acc1[i][jj] += a[i] * b[jj];
          acc2[i][jj] += c[i] * b[jj];
        }
    }
    __syncthreads();
  }
#pragma unroll
  for (int i = 0; i < 4; i++) {
    int r = m0 + ty * 4 + i;
#pragma unroll
    for (int jj = 0; jj < 4; jj++) {
      int c = n0 + tx * 4 + jj;
      C1[(size_t)r * ldc + c] = acc1[i][jj];
      C2[(size_t)r * ldc + c] = acc2[i][jj];
    }
  }
}

// ---------------- modulation / demodulation ----------------
// zcf[v'][j][l] = (2/N) * sum_u [ X[1024u+v'][l]*cj[j][1024u+v'] + X[1024u+1023-v'][l]*cj[j][...] ]
// zsf[v'][j][l] = (2/N) * sum_u [ X*sj(v') - X*sj(1023-v') ]
__global__ __launch_bounds__(256) void modulate_k(
    const float* __restrict__ X, const float* __restrict__ cj,
    const float* __restrict__ sj, float* __restrict__ zcf, float* __restrict__ zsf) {
  __shared__ float lca[1024], lsa[1024], lcb[1024], lsb[1024];
  int vp = blockIdx.x;
  int l = blockIdx.y * 256 + threadIdx.x;
  for (int idx = threadIdx.x; idx < 1024; idx += 256) {
    int j = idx >> 5, u = idx & 31;
    int na = (u << 10) + vp;
    int nb = (u << 10) + 1023 - vp;
    lca[idx] = cj[(j << 15) + na];
    lsa[idx] = sj[(j << 15) + na];
    lcb[idx] = cj[(j << 15) + nb];
    lsb[idx] = sj[(j << 15) + nb];
  }
  float xa[32], xb[32];
#pragma unroll
  for (int u = 0; u < 32; u++) {
    xa[u] = X[(size_t)((u << 10) + vp) * 512 + l];
    xb[u] = X[(size_t)((u << 10) + 1023 - vp) * 512 + l];
  }
  __syncthreads();
  const float sc = 2.0f / 32768.0f;
  for (int j = 0; j < 32; j++) {
    float ac = 0.f, as = 0.f;
#pragma unroll
    for (int u = 0; u < 32; u++) {
      ac += xa[u] * lca[(j << 5) + u] + xb[u] * lcb[(j << 5) + u];
      as += xa[u] * lsa[(j << 5) + u] - xb[u] * lsb[(j << 5) + u];
    }
    zcf[(size_t)vp * 16384 + (j << 9) + l] = ac * sc;
    zsf[(size_t)vp * 16384 + (j << 9) + l] = as * sc;
  }
}

// out[n][coff+l] = sum_j cj[j][n]*Pc[v'][j][l] -/+ sj[j][n]*Ps[v'][j][l]  + wv[n]*cw[l]
__global__ __launch_bounds__(256) void demod_k(
    const float* __restrict__ Pc, const float* __restrict__ Ps,
    const float* __restrict__ cj, const float* __restrict__ sj,
    const float* __restrict__ wv, const float* __restrict__ cw,
    float* __restrict__ out, int jcount, int coff) {
  __shared__ float lca[1024], lsa[1024], lcb[1024], lsb[1024];
  int vp = blockIdx.x;
  int l = blockIdx.y * 256 + threadIdx.x;
  int width = jcount << 9;
  for (int idx = threadIdx.x; idx < (jcount << 5); idx += 256) {
    int j = idx >> 5, u = idx & 31;
    int na = (u << 10) + vp;
    int nb = (u << 10) + 1023 - vp;
    lca[idx] = cj[(j << 15) + na];
    lsa[idx] = sj[(j << 15) + na];
    lcb[idx] = cj[(j << 15) + nb];
    lsb[idx] = sj[(j << 15) + nb];
  }
  __syncthreads();
  float acc_a[32] = {};
  float acc_b[32] = {};
  for (int j = 0; j < jcount; j++) {
    float pc = Pc[(size_t)vp * width + (j << 9) + l];
    float ps = Ps[(size_t)vp * width + (j << 9) + l];
#pragma unroll
    for (int u = 0; u < 32; u++) {
      acc_a[u] += lca[(j << 5) + u] * pc - lsa[(j << 5) + u] * ps;
      acc_b[u] += lcb[(j << 5) + u] * pc + lsb[(j << 5) + u] * ps;  // Ps odd in v-mirror
    }
  }
  float cl = cw[l];
  for (int u = 0; u < 32; u++) {
    int na = (u << 10) + vp;
    int nb = (u << 10) + 1023 - vp;
    out[(size_t)na * 1536 + coff + l] = acc_a[u] + wv[na] * cl;
    out[(size_t)nb * 1536 + coff + l] = acc_b[u] + wv[nb] * cl;
  }
}

// ---------------- launch ----------------
extern "C" void kernel_launch(void* const* d_in, const int* in_sizes, int n_in,
                              void* d_out, int out_size, void* d_ws, size_t ws_size,
                              hipStream_t stream) {
  const float* X  = (const float*)d_in[0];
  const float* W1 = (const float*)d_in[1];
  const float* b1 = (const float*)d_in[2];
  const float* W2 = (const float*)d_in[3];
  const float* b2 = (const float*)d_in[4];
  const float* W3 = (const float*)d_in[5];
  const float* b3 = (const float*)d_in[6];
  float* out = (float*)d_out;
  float* ws = (float*)d_ws;

  // workspace layout (floats); total 41,943,040 floats = 167.8 MB
  float* F    = ws + 0;         // 512x512
  float* Cm   = ws + 262144;    // 512x512
  float* Sm   = ws + 524288;    // 512x512
  float* Ptmp = ws + 786432;    // <=512x512 scratch
  float* M1   = ws + 1048576;
  float* M2   = ws + 1310720;
  float* M3   = ws + 1572864;
  float* c1   = ws + 1835008;
  float* c2   = ws + 1835520;
  float* c3   = ws + 1836032;
  float* v1   = ws + 1836544;   // 32768
  float* w2   = ws + 1869312;
  float* w3   = ws + 1902080;
  float* cj   = ws + 2097152;   // 32x32768
  float* sj   = ws + 3145728;
  float* Zraw = ws + 4194304;   // 512x16384 ; dead after Y2/Y3 -> aliased Pc3/Ps3
  float* Pc3  = ws + 4194304;   // 512x8192
  float* Ps3  = ws + 8388608;   // 512x8192
  float* Y2   = ws + 12582912;  // 16384x512
  float* Y3   = ws + 20971520;  // 8192x512
  float* Pc2  = ws + 25165824;  // 512x16384 ; also zcf (dead before inv2)
  float* Ps2  = ws + 33554432;  // 512x16384 ; also zsf
  float* zcf = Pc2;
  float* zsf = Ps2;

  dim3 blk(16, 16);

  // precompute tables / matrices
  fill_F_k<<<1024, 256, 0, stream>>>(F);
  fill_CS_k<<<1024, 256, 0, stream>>>(Cm, Sm);
  fill_cjsj_k<<<4096, 256, 0, stream>>>(cj, sj);
  fill_vw_k<<<128, 256, 0, stream>>>(v1, w2, w3);
  gemv_FT_k<<<2, 256, 0, stream>>>(F, b1, c1, 512);
  gemv_FT_k<<<2, 256, 0, stream>>>(F, b2, c2, 256);
  gemv_FT_k<<<2, 256, 0, stream>>>(F, b3, c3, 128);

  // M1 = F^T (W1^T F) ; M2 = F1^T (W2^T F1) ; M3 = F2^T (W3^T F2)
  gemm_tn_k<<<dim3(8, 8), blk, 0, stream>>>(W1, 512, F, 512, Ptmp, 512, 512);
  gemm_tn_k<<<dim3(8, 8), blk, 0, stream>>>(F, 512, Ptmp, 512, M1, 512, 512);
  gemm_tn_k<<<dim3(8, 4), blk, 0, stream>>>(W2, 256, F, 512, Ptmp, 512, 256);
  gemm_tn_k<<<dim3(8, 8), blk, 0, stream>>>(F, 512, Ptmp, 512, M2, 512, 256);
  gemm_tn_k<<<dim3(8, 2), blk, 0, stream>>>(W3, 128, F, 512, Ptmp, 512, 128);
  gemm_tn_k<<<dim3(8, 8), blk, 0, stream>>>(F, 512, Ptmp, 512, M3, 512, 128);

  // forward masked axis-0 DCT of X (j<32 superset covers both branches)
  modulate_k<<<dim3(512, 2), 256, 0, stream>>>(X, cj, sj, zcf, zsf);
  gemm_dual_nn_k<<<dim3(256, 8), blk, 0, stream>>>(Cm, Sm, 512, zcf, zsf, 16384,
                                                   Zraw, 16384, 512);
  fixup_k0_k<<<1, 512, 0, stream>>>(Zraw);

  // coefficient-domain L-matmuls: Y2 = Z(16384x512) @ M2 ; Y3 = Z[j<16] @ M3
  gemm_nn_k<<<dim3(8, 256), blk, 0, stream>>>(Zraw, 512, M2, 512, Y2, 512, 0, 512,
                                              nullptr, nullptr, 30, 30);
  gemm_nn_k<<<dim3(8, 128), blk, 0, stream>>>(Zraw, 512, M3, 512, Y3, 512, 0, 512,
                                              nullptr, nullptr, 4, 5);

  // inverse branch 2
  gemm_dual_tn2_k<<<dim3(256, 8), blk, 0, stream>>>(Cm, Sm, 512, Y2, 16384,
                                                    Pc2, Ps2, 16384, 512);
  demod_k<<<dim3(512, 2), 256, 0, stream>>>(Pc2, Ps2, cj, sj, w2, c2, out, 32, 512);

  // inverse branch 3
  gemm_dual_tn2_k<<<dim3(128, 8), blk, 0, stream>>>(Cm, Sm, 512, Y3, 8192,
                                                    Pc3, Ps3, 8192, 512);
  demod_k<<<dim3(512, 2), 256, 0, stream>>>(Pc3, Ps3, cj, sj, w3, c3, out, 16, 1024);

  // branch 1: out1 = X @ M1 + v1 c1^T
  gemm_nn_k<<<dim3(8, 512), blk, 0, stream>>>(X, 512, M1, 512, out, 1536, 0, 512,
                                              v1, c1, 30, 30);
}

// Round 2
// 1029.202 us; speedup vs baseline: 2.1401x; 2.1401x over previous
//
#include <hip/hip_runtime.h>
#include <cstddef>

// ============================================================================
// MultiWaveletTransform — algebraic refactor + f16 MFMA GEMMs.
//
// D = 32768-pt ortho DCT-II (axis 0 of x.reshape(-1,512)), F = 512-pt.
//   out1 = X M1 + v1 c1^T               (D cancels)
//   out2 = D^T P2 (D X) M2 + w2 c2^T    P2: k%64<32
//   out3 = D^T P3 (D X) M3 + w3 c3^T    P3: k%64<16
// Masked big DCT factorizes (k=64t+j, n=1024u+v) into modulation (u-sum,
// v-fold) + shared 512x512 cos/sin GEMMs. All heavy GEMMs (73 GFLOP, K=512)
// run as f16 MFMA 128x128-tile kernels: C[M][N] = A[M][512] . B^T[N][512].
// Scale 1/128 in modulate + 1/128 in M2T/M3T keeps fp16 in normal range.
// ============================================================================

#define PI_D 3.14159265358979323846

typedef _Float16 h8 __attribute__((ext_vector_type(8)));
typedef _Float16 h4 __attribute__((ext_vector_type(4)));
typedef float f4 __attribute__((ext_vector_type(4)));

// ---------------- fill kernels ----------------
__global__ void fill_F_k(float* __restrict__ F) {
  int idx = blockIdx.x * 256 + threadIdx.x;
  if (idx >= 512 * 512) return;
  int k = idx >> 9, m = idx & 511;
  int a = (k * (2 * m + 1)) & 2047;
  float ang = (float)(a * (PI_D / 1024.0));
  float s = (k == 0) ? 0.04419417382415922f : 0.0625f;
  F[idx] = s * cosf(ang);
}

// fp16 cos/sin matrices: Cmh[t][v], Smnh = -S, CmTh[v][t], SmTh[v][t]
__global__ void fill_CS_h_k(_Float16* __restrict__ Cmh, _Float16* __restrict__ Smnh,
                            _Float16* __restrict__ CmTh, _Float16* __restrict__ SmTh) {
  int idx = blockIdx.x * 256 + threadIdx.x;
  if (idx >= 512 * 512) return;
  int t = idx >> 9, v = idx & 511;
  int a = (t * (2 * v + 1)) & 2047;
  float ang = (float)(a * (PI_D / 1024.0));
  float c = cosf(ang), s = sinf(ang);
  Cmh[idx] = (_Float16)c;
  Smnh[idx] = (_Float16)(-s);
  CmTh[v * 512 + t] = (_Float16)c;
  SmTh[v * 512 + t] = (_Float16)s;
}

__global__ void fill_cjsj_k(float* __restrict__ cj, float* __restrict__ sj) {
  int idx = blockIdx.x * 256 + threadIdx.x;
  if (idx >= 32 * 32768) return;
  int j = idx >> 15, n = idx & 32767;
  int a = (j * (2 * n + 1)) & 131071;
  float ang = (float)(a * (PI_D / 65536.0));
  cj[idx] = cosf(ang);
  sj[idx] = sinf(ang);
}

__global__ void fill_vw_k(float* __restrict__ v1, float* __restrict__ w2,
                          float* __restrict__ w3) {
  int n = blockIdx.x * 256 + threadIdx.x;
  if (n >= 32768) return;
  const double s1 = 0.005524271728019903;
  const double s2 = 0.0078125;
  double th = (2 * n + 1) * (PI_D / 65536.0);
  double c = cos(th), s = sin(th);
  double Dr = 1.0 - c, Di = -s;
  double dd = Dr * Dr + Di * Di;
  double Nr = 1.0, Ni = (n & 1) ? 1.0 : -1.0;
  double vre = (Nr * Dr + Ni * Di) / dd;
  v1[n] = (float)(s2 * vre + (s1 - s2));
  int m64 = (2 * n + 1) & 2047;
  double a64 = m64 * (PI_D / 1024.0);
  double D64r = 1.0 - cos(a64), D64i = -sin(a64);
  double d64 = D64r * D64r + D64i * D64i;
  double Gr = (Nr * D64r + Ni * D64i) / d64;
  double Gi = (Ni * D64r - Nr * D64i) / d64;
  int m32 = (2 * n + 1) & 4095;
  double a32 = m32 * (PI_D / 2048.0);
  double S32nr = 1.0 - cos(a32), S32ni = -sin(a32);
  double S32r = (S32nr * Dr + S32ni * Di) / dd;
  double S32i = (S32ni * Dr - S32nr * Di) / dd;
  w2[n] = (float)(s2 * (S32r * Gr - S32i * Gi) + (s1 - s2));
  int m16 = (2 * n + 1) & 8191;
  double a16 = m16 * (PI_D / 4096.0);
  double S16nr = 1.0 - cos(a16), S16ni = -sin(a16);
  double S16r = (S16nr * Dr + S16ni * Di) / dd;
  double S16i = (S16ni * Dr - S16nr * Di) / dd;
  w3[n] = (float)(s2 * (S16r * Gr - S16i * Gi) + (s1 - s2));
}

__global__ void gemv_FT_k(const float* __restrict__ F, const float* __restrict__ b,
                          float* __restrict__ out, int Kd) {
  int l = blockIdx.x * 256 + threadIdx.x;
  if (l >= 512) return;
  float acc = 0.f;
  for (int m = 0; m < Kd; m++) acc += F[m * 512 + l] * b[m];
  out[l] = acc;
}

__global__ void fixup_h_k(_Float16* __restrict__ Z) {
  int l = threadIdx.x;  // t=0,j=0 row: first 512; s_0^2 = 1/N not 2/N
  if (l < 512) Z[l] = (_Float16)((float)Z[l] * 0.5f);
}

__global__ void conv_xh_k(const float* __restrict__ X, _Float16* __restrict__ Xh) {
  int i = blockIdx.x * 256 + threadIdx.x;  // 4194304 float4's
  float4 v = ((const float4*)X)[i];
  h4 o;
  o[0] = (_Float16)v.x; o[1] = (_Float16)v.y; o[2] = (_Float16)v.z; o[3] = (_Float16)v.w;
  ((h4*)Xh)[i] = o;
}

// ---------------- small fp32 GEMM for precompute: C = A^T B ----------------
#define BK 16
#define LDP 68
__global__ __launch_bounds__(256) void gemm_tn_k(
    const float* __restrict__ A, int lda, const float* __restrict__ B, int ldb,
    float* __restrict__ Cf, _Float16* __restrict__ C16, int Kd, float scale) {
  __shared__ float As[BK][LDP];
  __shared__ float Bs[BK][LDP];
  int tx = threadIdx.x, ty = threadIdx.y;
  int tid = ty * 16 + tx;
  int m0 = blockIdx.y * 64, n0 = blockIdx.x * 64;
  float acc[4][4] = {};
  for (int k0 = 0; k0 < Kd; k0 += BK) {
#pragma unroll
    for (int i = 0; i < 4; i++) {
      int idx = tid + i * 256;
      int m = idx & 63, kk = idx >> 6;
      As[kk][m] = A[(size_t)(k0 + kk) * lda + m0 + m];
      Bs[kk][m] = B[(size_t)(k0 + kk) * ldb + n0 + m];
    }
    __syncthreads();
#pragma unroll
    for (int kk = 0; kk < BK; kk++) {
      float4 a4 = *(const float4*)&As[kk][ty * 4];
      float4 b4 = *(const float4*)&Bs[kk][tx * 4];
      float a[4] = {a4.x, a4.y, a4.z, a4.w};
      float b[4] = {b4.x, b4.y, b4.z, b4.w};
#pragma unroll
      for (int i = 0; i < 4; i++)
#pragma unroll
        for (int jj = 0; jj < 4; jj++) acc[i][jj] += a[i] * b[jj];
    }
    __syncthreads();
  }
#pragma unroll
  for (int i = 0; i < 4; i++) {
    int r = m0 + ty * 4 + i;
#pragma unroll
    for (int jj = 0; jj < 4; jj++) {
      int c = n0 + tx * 4 + jj;
      if (C16) C16[(size_t)r * 512 + c] = (_Float16)(acc[i][jj] * scale);
      else Cf[(size_t)r * 512 + c] = acc[i][jj];
    }
  }
}

// ---------------- fp16 tiled transpose (out[c][r] = in[r][c]) ----------------
__global__ __launch_bounds__(256) void transpose_h_k(const _Float16* __restrict__ in,
                                                     _Float16* __restrict__ out,
                                                     int R, int C) {
  __shared__ _Float16 t[64][66];
  int tid = threadIdx.x;
  int bx = blockIdx.x * 64;  // col base in 'in'
  int by = blockIdx.y * 64;  // row base in 'in'
  int cx = (tid & 15) * 4;
  int ry = tid >> 4;
#pragma unroll
  for (int p = 0; p < 4; p++) {
    int r = ry + p * 16;
    h4 v = *(const h4*)&in[(size_t)(by + r) * C + bx + cx];
    t[r][cx + 0] = v[0]; t[r][cx + 1] = v[1]; t[r][cx + 2] = v[2]; t[r][cx + 3] = v[3];
  }
  __syncthreads();
#pragma unroll
  for (int p = 0; p < 4; p++) {
    int r2 = ry + p * 16;
    h4 v;
    v[0] = t[cx + 0][r2]; v[1] = t[cx + 1][r2]; v[2] = t[cx + 2][r2]; v[3] = t[cx + 3][r2];
    *(h4*)&out[(size_t)(bx + r2) * R + by + cx] = v;
  }
}

// ---------------- f16 MFMA GEMM: C[M][N] = A[M][512] . B^T[N][512] ----------
// MODE 0: plain, fp16 out (A-row remap via sb/tb)
// MODE 1: C = A1 B1^T + A2 B2^T (A2 pre-negated), fp16 out
// MODE 2: C1 = A1 B^T, C2 = A2 B^T (shared B), fp16 outs
// MODE 3: plain, fp32 out, + u[r]*w[c] rank-1, ldc/coff
__device__ __forceinline__ void async16(const _Float16* g, _Float16* l) {
  __builtin_amdgcn_global_load_lds((const __attribute__((address_space(1))) void*)g,
                                   (__attribute__((address_space(3))) void*)l, 16, 0, 0);
}

template <int MODE>
__global__ __launch_bounds__(256) void mfma_gemm_k(
    const _Float16* __restrict__ A1, const _Float16* __restrict__ A2,
    const _Float16* __restrict__ B1, const _Float16* __restrict__ B2,
    void* __restrict__ C1, void* __restrict__ C2, int ldc, int coff,
    const float* __restrict__ u, const float* __restrict__ wvec, int sb, int tb) {
  constexpr bool DA = (MODE == 1 || MODE == 2);
  constexpr bool DB = (MODE == 1);
  __shared__ __align__(16) _Float16 As[(DA ? 2 : 1) * 4096];
  __shared__ __align__(16) _Float16 Bs[(DB ? 2 : 1) * 4096];
  const int tid = threadIdx.x;
  const int lane = tid & 63;
  const int wm = (tid >> 6) & 1, wn = tid >> 7;
  const int m0 = blockIdx.y * 128, n0 = blockIdx.x * 128;
  const int srow = tid >> 2, scol = (tid & 3) * 8;
  const int mask = (1 << sb) - 1;
  f4 acc[4][4] = {};
  f4 acc2[4][4] = {};
  const int fm = lane & 15, fko = (lane >> 4) * 8;
  for (int k0 = 0; k0 < 512; k0 += 32) {
#pragma unroll
    for (int i = 0; i < 2; i++) {
      int r = m0 + i * 64 + srow;
      int pr = ((r >> sb) << tb) | (r & mask);
      async16(A1 + (size_t)pr * 512 + k0 + scol, &As[i * 2048 + tid * 8]);
      if constexpr (DA)
        async16(A2 + (size_t)pr * 512 + k0 + scol, &As[4096 + i * 2048 + tid * 8]);
      int rb = n0 + i * 64 + srow;
      async16(B1 + (size_t)rb * 512 + k0 + scol, &Bs[i * 2048 + tid * 8]);
      if constexpr (DB)
        async16(B2 + (size_t)rb * 512 + k0 + scol, &Bs[4096 + i * 2048 + tid * 8]);
    }
    __syncthreads();
    h8 af[4], bf[4], af2[4], bf2[4];
#pragma unroll
    for (int i = 0; i < 4; i++) {
      int ro = (wm * 64 + i * 16 + fm) * 32 + fko;
      af[i] = *(const h8*)&As[ro];
      if constexpr (DA) af2[i] = *(const h8*)&As[4096 + ro];
    }
#pragma unroll
    for (int j = 0; j < 4; j++) {
      int co = (wn * 64 + j * 16 + fm) * 32 + fko;
      bf[j] = *(const h8*)&Bs[co];
      if constexpr (DB) bf2[j] = *(const h8*)&Bs[4096 + co];
    }
#pragma unroll
    for (int i = 0; i < 4; i++)
#pragma unroll
      for (int j = 0; j < 4; j++) {
        acc[i][j] = __builtin_amdgcn_mfma_f32_16x16x32_f16(af[i], bf[j], acc[i][j], 0, 0, 0);
        if constexpr (MODE == 1)
          acc[i][j] = __builtin_amdgcn_mfma_f32_16x16x32_f16(af2[i], bf2[j], acc[i][j], 0, 0, 0);
        if constexpr (MODE == 2)
          acc2[i][j] = __builtin_amdgcn_mfma_f32_16x16x32_f16(af2[i], bf[j], acc2[i][j], 0, 0, 0);
      }
    __syncthreads();
  }
  const int er = (lane >> 4) * 4, ec = lane & 15;
#pragma unroll
  for (int i = 0; i < 4; i++) {
    int gr0 = m0 + wm * 64 + i * 16 + er;
#pragma unroll
    for (int j = 0; j < 4; j++) {
      int gc = n0 + wn * 64 + j * 16 + ec;
#pragma unroll
      for (int r = 0; r < 4; r++) {
        size_t off = (size_t)(gr0 + r) * ldc + coff + gc;
        if constexpr (MODE == 3) {
          ((float*)C1)[off] = acc[i][j][r] + u[gr0 + r] * wvec[gc];
        } else if constexpr (MODE == 2) {
          ((_Float16*)C1)[off] = (_Float16)acc[i][j][r];
          ((_Float16*)C2)[off] = (_Float16)acc2[i][j][r];
        } else {
          ((_Float16*)C1)[off] = (_Float16)acc[i][j][r];
        }
      }
    }
  }
}

// ---------------- modulation / demodulation ----------------
__global__ __launch_bounds__(256) void modulate_k(
    const float* __restrict__ X, const float* __restrict__ cj,
    const float* __restrict__ sj, _Float16* __restrict__ zcf,
    _Float16* __restrict__ zsf) {
  __shared__ float lca[1024], lsa[1024], lcb[1024], lsb[1024];
  int vp = blockIdx.x;
  int l = blockIdx.y * 256 + threadIdx.x;
  for (int idx = threadIdx.x; idx < 1024; idx += 256) {
    int j = idx >> 5, u = idx & 31;
    int na = (u << 10) + vp;
    int nb = (u << 10) + 1023 - vp;
    lca[idx] = cj[(j << 15) + na];
    lsa[idx] = sj[(j << 15) + na];
    lcb[idx] = cj[(j << 15) + nb];
    lsb[idx] = sj[(j << 15) + nb];
  }
  float xa[32], xb[32];
#pragma unroll
  for (int u = 0; u < 32; u++) {
    xa[u] = X[(size_t)((u << 10) + vp) * 512 + l];
    xb[u] = X[(size_t)((u << 10) + 1023 - vp) * 512 + l];
  }
  __syncthreads();
  const float sc = 0.0078125f;  // sqrt(2/32768); the other 1/128 is in M2T/M3T
  for (int j = 0; j < 32; j++) {
    float ac = 0.f, as = 0.f;
#pragma unroll
    for (int u = 0; u < 32; u++) {
      ac += xa[u] * lca[(j << 5) + u] + xb[u] * lcb[(j << 5) + u];
      as += xa[u] * lsa[(j << 5) + u] - xb[u] * lsb[(j << 5) + u];
    }
    zcf[(size_t)vp * 16384 + (j << 9) + l] = (_Float16)(ac * sc);
    zsf[(size_t)vp * 16384 + (j << 9) + l] = (_Float16)(as * sc);
  }
}

__global__ __launch_bounds__(256) void demod_k(
    const _Float16* __restrict__ Pc, const _Float16* __restrict__ Ps,
    const float* __restrict__ cj, const float* __restrict__ sj,
    const float* __restrict__ wv, const float* __restrict__ cw,
    float* __restrict__ out, int jcount, int coff) {
  __shared__ float lca[1024], lsa[1024], lcb[1024], lsb[1024];
  int vp = blockIdx.x;
  int l = blockIdx.y * 256 + threadIdx.x;
  int width = jcount << 9;
  for (int idx = threadIdx.x; idx < (jcount << 5); idx += 256) {
    int j = idx >> 5, u = idx & 31;
    int na = (u << 10) + vp;
    int nb = (u << 10) + 1023 - vp;
    lca[idx] = cj[(j << 15) + na];
    lsa[idx] = sj[(j << 15) + na];
    lcb[idx] = cj[(j << 15) + nb];
    lsb[idx] = sj[(j << 15) + nb];
  }
  __syncthreads();
  float acc_a[32] = {};
  float acc_b[32] = {};
  for (int j = 0; j < jcount; j++) {
    float pc = (float)Pc[(size_t)vp * width + (j << 9) + l];
    float ps = (float)Ps[(size_t)vp * width + (j << 9) + l];
#pragma unroll
    for (int u = 0; u < 32; u++) {
      acc_a[u] += lca[(j << 5) + u] * pc - lsa[(j << 5) + u] * ps;
      acc_b[u] += lcb[(j << 5) + u] * pc + lsb[(j << 5) + u] * ps;
    }
  }
  float cl = cw[l];
  for (int u = 0; u < 32; u++) {
    int na = (u << 10) + vp;
    int nb = (u << 10) + 1023 - vp;
    out[(size_t)na * 1536 + coff + l] = acc_a[u] + wv[na] * cl;
    out[(size_t)nb * 1536 + coff + l] = acc_b[u] + wv[nb] * cl;
  }
}

// ---------------- launch ----------------
extern "C" void kernel_launch(void* const* d_in, const int* in_sizes, int n_in,
                              void* d_out, int out_size, void* d_ws, size_t ws_size,
                              hipStream_t stream) {
  const float* X  = (const float*)d_in[0];
  const float* W1 = (const float*)d_in[1];
  const float* b1 = (const float*)d_in[2];
  const float* W2 = (const float*)d_in[3];
  const float* b2 = (const float*)d_in[4];
  const float* W3 = (const float*)d_in[5];
  const float* b3 = (const float*)d_in[6];
  float* out = (float*)d_out;
  char* w = (char*)d_ws;
  const size_t MB = 1024 * 1024;

  // ---- workspace layout (peak 152 MiB < 160 MiB) ----
  float* F    = (float*)(w);                       // 1 MB
  float* cj   = (float*)(w + 1 * MB);              // 4 MB
  float* sj   = (float*)(w + 5 * MB);              // 4 MB
  float* v1   = (float*)(w + 9 * MB);              // 128 KB
  float* w2v  = (float*)(w + 9 * MB + 131072);
  float* w3v  = (float*)(w + 9 * MB + 262144);
  float* c1   = (float*)(w + 9 * MB + 393216);
  float* c2   = (float*)(w + 9 * MB + 395264);
  float* c3   = (float*)(w + 9 * MB + 397312);
  float* Ptmp = (float*)(w + 10 * MB);             // 1 MB fp32
  _Float16* CmTh = (_Float16*)(w + 11 * MB);
  _Float16* SmTh = (_Float16*)(w + 11 * MB + 524288);
  _Float16* Cmh  = (_Float16*)(w + 12 * MB);
  _Float16* Smnh = (_Float16*)(w + 12 * MB + 524288);
  _Float16* M1T  = (_Float16*)(w + 13 * MB);
  _Float16* M2T  = (_Float16*)(w + 13 * MB + 524288);
  _Float16* M3T  = (_Float16*)(w + 14 * MB);
  _Float16* Xh   = (_Float16*)(w + 16 * MB);       // 32 MB
  // slot A (48..80): zc/zs -> Pc2/Ps2 -> Pc3/Ps3
  _Float16* zc   = (_Float16*)(w + 48 * MB);
  _Float16* zs   = (_Float16*)(w + 64 * MB);
  _Float16* Pc2h = (_Float16*)(w + 48 * MB);
  _Float16* Ps2h = (_Float16*)(w + 64 * MB);
  _Float16* Pc3h = (_Float16*)(w + 48 * MB);
  _Float16* Ps3h = (_Float16*)(w + 56 * MB);
  // slot B (80..112): zcT/zsT -> Y2T/Y3T
  _Float16* zcT  = (_Float16*)(w + 80 * MB);
  _Float16* zsT  = (_Float16*)(w + 96 * MB);
  _Float16* Y2T  = (_Float16*)(w + 80 * MB);
  _Float16* Y3T  = (_Float16*)(w + 96 * MB);
  _Float16* Zh   = (_Float16*)(w + 112 * MB);      // 16 MB
  _Float16* Y2   = (_Float16*)(w + 128 * MB);      // 16 MB
  _Float16* Y3   = (_Float16*)(w + 144 * MB);      // 8 MB

  dim3 blk(16, 16);

  // precompute tables
  fill_F_k<<<1024, 256, 0, stream>>>(F);
  fill_CS_h_k<<<1024, 256, 0, stream>>>(Cmh, Smnh, CmTh, SmTh);
  fill_cjsj_k<<<4096, 256, 0, stream>>>(cj, sj);
  fill_vw_k<<<128, 256, 0, stream>>>(v1, w2v, w3v);
  gemv_FT_k<<<2, 256, 0, stream>>>(F, b1, c1, 512);
  gemv_FT_k<<<2, 256, 0, stream>>>(F, b2, c2, 256);
  gemv_FT_k<<<2, 256, 0, stream>>>(F, b3, c3, 128);

  // MxT = (F^T Wx^T F)^T as fp16 (scale 1/128 for M2/M3)
  gemm_tn_k<<<dim3(8, 8), blk, 0, stream>>>(W1, 512, F, 512, Ptmp, nullptr, 512, 1.f);
  gemm_tn_k<<<dim3(8, 8), blk, 0, stream>>>(Ptmp, 512, F, 512, nullptr, M1T, 512, 1.f);
  gemm_tn_k<<<dim3(8, 4), blk, 0, stream>>>(W2, 256, F, 512, Ptmp, nullptr, 256, 1.f);
  gemm_tn_k<<<dim3(8, 8), blk, 0, stream>>>(Ptmp, 512, F, 512, nullptr, M2T, 256, 0.0078125f);
  gemm_tn_k<<<dim3(8, 2), blk, 0, stream>>>(W3, 128, F, 512, Ptmp, nullptr, 128, 1.f);
  gemm_tn_k<<<dim3(8, 8), blk, 0, stream>>>(Ptmp, 512, F, 512, nullptr, M3T, 128, 0.0078125f);

  // X -> fp16
  conv_xh_k<<<16384, 256, 0, stream>>>(X, Xh);

  // forward: modulate -> transpose -> dual GEMM -> fixup
  modulate_k<<<dim3(512, 2), 256, 0, stream>>>(X, cj, sj, zc, zs);
  transpose_h_k<<<dim3(256, 8), 256, 0, stream>>>(zc, zcT, 512, 16384);
  transpose_h_k<<<dim3(256, 8), 256, 0, stream>>>(zs, zsT, 512, 16384);
  mfma_gemm_k<1><<<dim3(128, 4), 256, 0, stream>>>(Cmh, Smnh, zcT, zsT, Zh, nullptr,
                                                   16384, 0, nullptr, nullptr, 30, 30);
  fixup_h_k<<<1, 512, 0, stream>>>(Zh);

  // coefficient-domain L-matmuls
  mfma_gemm_k<0><<<dim3(4, 128), 256, 0, stream>>>(Zh, nullptr, M2T, nullptr, Y2, nullptr,
                                                   512, 0, nullptr, nullptr, 30, 30);
  mfma_gemm_k<0><<<dim3(4, 64), 256, 0, stream>>>(Zh, nullptr, M3T, nullptr, Y3, nullptr,
                                                  512, 0, nullptr, nullptr, 4, 5);

  // inverse branch 2
  transpose_h_k<<<dim3(256, 8), 256, 0, stream>>>(Y2, Y2T, 512, 16384);
  mfma_gemm_k<2><<<dim3(128, 4), 256, 0, stream>>>(CmTh, SmTh, Y2T, nullptr, Pc2h, Ps2h,
                                                   16384, 0, nullptr, nullptr, 30, 30);
  demod_k<<<dim3(512, 2), 256, 0, stream>>>(Pc2h, Ps2h, cj, sj, w2v, c2, out, 32, 512);

  // inverse branch 3
  transpose_h_k<<<dim3(128, 8), 256, 0, stream>>>(Y3, Y3T, 512, 8192);
  mfma_gemm_k<2><<<dim3(64, 4), 256, 0, stream>>>(CmTh, SmTh, Y3T, nullptr, Pc3h, Ps3h,
                                                  8192, 0, nullptr, nullptr, 30, 30);
  demod_k<<<dim3(512, 2), 256, 0, stream>>>(Pc3h, Ps3h, cj, sj, w3v, c3, out, 16, 1024);

  // branch 1: out1 = X M1 + v1 c1^T
  mfma_gemm_k<3><<<dim3(4, 256), 256, 0, stream>>>(Xh, nullptr, M1T, nullptr, out, nullptr,
                                                   1536, 0, v1, c1, 30, 30);
}

// Round 3
// 836.790 us; speedup vs baseline: 2.6322x; 1.2299x over previous
//
#include <hip/hip_runtime.h>
#include <cstddef>

// ============================================================================
// MultiWaveletTransform — algebraic refactor, all heavy math on MFMA.
//
// D = 32768-pt ortho DCT-II (axis 0 of x.reshape(-1,512)), F = 512-pt.
//   out1 = X M1 + v1 c1^T               (D cancels)
//   out2 = D^T P2 (D X) M2 + w2 c2^T    P2: k%64<32
//   out3 = D^T P3 (D X) M3 + w3 c3^T    P3: k%64<16
// Masked big DCT factorizes (k=64t+j, n=1024u+v) into per-vp modulation
// (u-sum + v-fold, now a 32x64 @ 64x512 MFMA batch) + shared 512x512 cos/sin
// GEMMs (128-tile MFMA). Demodulation is the mirrored MFMA batch. M-matrices
// precomputed by a small MFMA GEMM with LDS-transpose staging.
// ============================================================================

#define PI_D 3.14159265358979323846

typedef _Float16 h8 __attribute__((ext_vector_type(8)));
typedef _Float16 h4 __attribute__((ext_vector_type(4)));
typedef float f4 __attribute__((ext_vector_type(4)));

#define MFMA16(a, b, c) __builtin_amdgcn_mfma_f32_16x16x32_f16(a, b, c, 0, 0, 0)

// ---------------- fill kernels ----------------
__global__ void fill_F_k(float* __restrict__ F) {
  int idx = blockIdx.x * 256 + threadIdx.x;
  if (idx >= 512 * 512) return;
  int k = idx >> 9, m = idx & 511;
  int a = (k * (2 * m + 1)) & 2047;
  float ang = (float)(a * (PI_D / 1024.0));
  float s = (k == 0) ? 0.04419417382415922f : 0.0625f;
  F[idx] = s * cosf(ang);
}

__global__ void fill_CS_h_k(_Float16* __restrict__ Cmh, _Float16* __restrict__ Smnh,
                            _Float16* __restrict__ CmTh, _Float16* __restrict__ SmTh) {
  int idx = blockIdx.x * 256 + threadIdx.x;
  if (idx >= 512 * 512) return;
  int t = idx >> 9, v = idx & 511;
  int a = (t * (2 * v + 1)) & 2047;
  float ang = (float)(a * (PI_D / 1024.0));
  float c = cosf(ang), s = sinf(ang);
  Cmh[idx] = (_Float16)c;
  Smnh[idx] = (_Float16)(-s);
  CmTh[v * 512 + t] = (_Float16)c;
  SmTh[v * 512 + t] = (_Float16)s;
}

__global__ void fill_cjsj_k(float* __restrict__ cj, float* __restrict__ sj) {
  int idx = blockIdx.x * 256 + threadIdx.x;
  if (idx >= 32 * 32768) return;
  int j = idx >> 15, n = idx & 32767;
  int a = (j * (2 * n + 1)) & 131071;
  float ang = (float)(a * (PI_D / 65536.0));
  cj[idx] = cosf(ang);
  sj[idx] = sinf(ang);
}

__global__ void fill_vw_k(float* __restrict__ v1, float* __restrict__ w2,
                          float* __restrict__ w3) {
  int n = blockIdx.x * 256 + threadIdx.x;
  if (n >= 32768) return;
  const double s1 = 0.005524271728019903;
  const double s2 = 0.0078125;
  double th = (2 * n + 1) * (PI_D / 65536.0);
  double c = cos(th), s = sin(th);
  double Dr = 1.0 - c, Di = -s;
  double dd = Dr * Dr + Di * Di;
  double Nr = 1.0, Ni = (n & 1) ? 1.0 : -1.0;
  double vre = (Nr * Dr + Ni * Di) / dd;
  v1[n] = (float)(s2 * vre + (s1 - s2));
  int m64 = (2 * n + 1) & 2047;
  double a64 = m64 * (PI_D / 1024.0);
  double D64r = 1.0 - cos(a64), D64i = -sin(a64);
  double d64 = D64r * D64r + D64i * D64i;
  double Gr = (Nr * D64r + Ni * D64i) / d64;
  double Gi = (Ni * D64r - Nr * D64i) / d64;
  int m32 = (2 * n + 1) & 4095;
  double a32 = m32 * (PI_D / 2048.0);
  double S32nr = 1.0 - cos(a32), S32ni = -sin(a32);
  double S32r = (S32nr * Dr + S32ni * Di) / dd;
  double S32i = (S32ni * Dr - S32nr * Di) / dd;
  w2[n] = (float)(s2 * (S32r * Gr - S32i * Gi) + (s1 - s2));
  int m16 = (2 * n + 1) & 8191;
  double a16 = m16 * (PI_D / 4096.0);
  double S16nr = 1.0 - cos(a16), S16ni = -sin(a16);
  double S16r = (S16nr * Dr + S16ni * Di) / dd;
  double S16i = (S16ni * Dr - S16nr * Di) / dd;
  w3[n] = (float)(s2 * (S16r * Gr - S16i * Gi) + (s1 - s2));
}

__global__ void gemv_FT_k(const float* __restrict__ F, const float* __restrict__ b,
                          float* __restrict__ out, int Kd) {
  int l = blockIdx.x * 256 + threadIdx.x;
  if (l >= 512) return;
  float acc = 0.f;
  for (int m = 0; m < Kd; m++) acc += F[m * 512 + l] * b[m];
  out[l] = acc;
}

__global__ void fixup_h_k(_Float16* __restrict__ Z) {
  int l = threadIdx.x;  // t=0,j=0 row: s_0^2 = 1/N not 2/N
  if (l < 512) Z[l] = (_Float16)((float)Z[l] * 0.5f);
}

__global__ void conv_xh_k(const float* __restrict__ X, _Float16* __restrict__ Xh) {
  int i = blockIdx.x * 256 + threadIdx.x;
  float4 v = ((const float4*)X)[i];
  h4 o;
  o[0] = (_Float16)v.x; o[1] = (_Float16)v.y; o[2] = (_Float16)v.z; o[3] = (_Float16)v.w;
  ((h4*)Xh)[i] = o;
}

// ---------------- small MFMA GEMM for precompute ----------------
// C[m][n] = sum_k A'[k][m] * B[k][n]  (B always [K][N] fp32, transpose-staged;
// A: transA=1 -> A[k][m], transA=0 -> A[m][k]).  Out fp32 or f16*scale, ldc=512.
__global__ __launch_bounds__(256) void sgemm_k(
    const float* __restrict__ A, int lda, int transA,
    const float* __restrict__ B, int ldb,
    float* __restrict__ Cf, _Float16* __restrict__ C16, int K, float scale) {
  __shared__ _Float16 As[128 * 40];
  __shared__ _Float16 Bs[128 * 40];
  const int tid = threadIdx.x;
  const int lane = tid & 63;
  const int wm = (tid >> 6) & 1, wn = tid >> 7;
  const int m0 = blockIdx.y * 128, n0 = blockIdx.x * 128;
  const int fm = lane & 15, fko = (lane >> 4) * 8;
  f4 acc[4][4] = {};
  for (int k0 = 0; k0 < K; k0 += 32) {
    if (transA) {
#pragma unroll
      for (int i = 0; i < 4; i++) {
        int idx4 = tid + i * 256;
        int kk = idx4 & 31, mc = (idx4 >> 5) * 4;
        float4 v = *(const float4*)&A[(size_t)(k0 + kk) * lda + m0 + mc];
        As[(mc + 0) * 40 + kk] = (_Float16)v.x;
        As[(mc + 1) * 40 + kk] = (_Float16)v.y;
        As[(mc + 2) * 40 + kk] = (_Float16)v.z;
        As[(mc + 3) * 40 + kk] = (_Float16)v.w;
      }
    } else {
#pragma unroll
      for (int i = 0; i < 4; i++) {
        int idx4 = tid + i * 256;
        int mm = idx4 >> 3, kc = (idx4 & 7) * 4;
        float4 v = *(const float4*)&A[(size_t)(m0 + mm) * lda + k0 + kc];
        h4 o;
        o[0] = (_Float16)v.x; o[1] = (_Float16)v.y; o[2] = (_Float16)v.z; o[3] = (_Float16)v.w;
        *(h4*)&As[mm * 40 + kc] = o;
      }
    }
#pragma unroll
    for (int i = 0; i < 4; i++) {
      int idx4 = tid + i * 256;
      int kk = idx4 & 31, nc = (idx4 >> 5) * 4;
      float4 v = *(const float4*)&B[(size_t)(k0 + kk) * ldb + n0 + nc];
      Bs[(nc + 0) * 40 + kk] = (_Float16)v.x;
      Bs[(nc + 1) * 40 + kk] = (_Float16)v.y;
      Bs[(nc + 2) * 40 + kk] = (_Float16)v.z;
      Bs[(nc + 3) * 40 + kk] = (_Float16)v.w;
    }
    __syncthreads();
    h8 af[4], bf[4];
#pragma unroll
    for (int i = 0; i < 4; i++) af[i] = *(const h8*)&As[(wm * 64 + i * 16 + fm) * 40 + fko];
#pragma unroll
    for (int j = 0; j < 4; j++) bf[j] = *(const h8*)&Bs[(wn * 64 + j * 16 + fm) * 40 + fko];
#pragma unroll
    for (int i = 0; i < 4; i++)
#pragma unroll
      for (int j = 0; j < 4; j++) acc[i][j] = MFMA16(af[i], bf[j], acc[i][j]);
    __syncthreads();
  }
  const int er = (lane >> 4) * 4, ec = lane & 15;
#pragma unroll
  for (int i = 0; i < 4; i++) {
    int gr0 = m0 + wm * 64 + i * 16 + er;
#pragma unroll
    for (int j = 0; j < 4; j++) {
      int gc = n0 + wn * 64 + j * 16 + ec;
#pragma unroll
      for (int r = 0; r < 4; r++) {
        size_t off = (size_t)(gr0 + r) * 512 + gc;
        if (C16) C16[off] = (_Float16)(acc[i][j][r] * scale);
        else Cf[off] = acc[i][j][r];
      }
    }
  }
}

// ---------------- fp16 tiled transpose ----------------
__global__ __launch_bounds__(256) void transpose_h_k(const _Float16* __restrict__ in,
                                                     _Float16* __restrict__ out,
                                                     int R, int C) {
  __shared__ _Float16 t[64][66];
  int tid = threadIdx.x;
  int bx = blockIdx.x * 64;
  int by = blockIdx.y * 64;
  int cx = (tid & 15) * 4;
  int ry = tid >> 4;
#pragma unroll
  for (int p = 0; p < 4; p++) {
    int r = ry + p * 16;
    h4 v = *(const h4*)&in[(size_t)(by + r) * C + bx + cx];
    t[r][cx + 0] = v[0]; t[r][cx + 1] = v[1]; t[r][cx + 2] = v[2]; t[r][cx + 3] = v[3];
  }
  __syncthreads();
#pragma unroll
  for (int p = 0; p < 4; p++) {
    int r2 = ry + p * 16;
    h4 v;
    v[0] = t[cx + 0][r2]; v[1] = t[cx + 1][r2]; v[2] = t[cx + 2][r2]; v[3] = t[cx + 3][r2];
    *(h4*)&out[(size_t)(bx + r2) * R + by + cx] = v;
  }
}

// ---------------- main f16 MFMA GEMM: C[M][N] = A[M][512] . B^T[N][512] -----
__device__ __forceinline__ void async16(const _Float16* g, _Float16* l) {
  __builtin_amdgcn_global_load_lds((const __attribute__((address_space(1))) void*)g,
                                   (__attribute__((address_space(3))) void*)l, 16, 0, 0);
}

template <int MODE>
__global__ __launch_bounds__(256) void mfma_gemm_k(
    const _Float16* __restrict__ A1, const _Float16* __restrict__ A2,
    const _Float16* __restrict__ B1, const _Float16* __restrict__ B2,
    void* __restrict__ C1, void* __restrict__ C2, int ldc, int coff,
    const float* __restrict__ u, const float* __restrict__ wvec, int sb, int tb) {
  constexpr bool DA = (MODE == 1 || MODE == 2);
  constexpr bool DB = (MODE == 1);
  __shared__ __align__(16) _Float16 As[(DA ? 2 : 1) * 4096];
  __shared__ __align__(16) _Float16 Bs[(DB ? 2 : 1) * 4096];
  const int tid = threadIdx.x;
  const int lane = tid & 63;
  const int wm = (tid >> 6) & 1, wn = tid >> 7;
  const int m0 = blockIdx.y * 128, n0 = blockIdx.x * 128;
  const int srow = tid >> 2, scol = (tid & 3) * 8;
  const int mask = (1 << sb) - 1;
  f4 acc[4][4] = {};
  f4 acc2[4][4] = {};
  const int fm = lane & 15, fko = (lane >> 4) * 8;
  for (int k0 = 0; k0 < 512; k0 += 32) {
#pragma unroll
    for (int i = 0; i < 2; i++) {
      int r = m0 + i * 64 + srow;
      int pr = ((r >> sb) << tb) | (r & mask);
      async16(A1 + (size_t)pr * 512 + k0 + scol, &As[i * 2048 + tid * 8]);
      if constexpr (DA)
        async16(A2 + (size_t)pr * 512 + k0 + scol, &As[4096 + i * 2048 + tid * 8]);
      int rb = n0 + i * 64 + srow;
      async16(B1 + (size_t)rb * 512 + k0 + scol, &Bs[i * 2048 + tid * 8]);
      if constexpr (DB)
        async16(B2 + (size_t)rb * 512 + k0 + scol, &Bs[4096 + i * 2048 + tid * 8]);
    }
    __syncthreads();
    h8 af[4], bf[4], af2[4], bf2[4];
#pragma unroll
    for (int i = 0; i < 4; i++) {
      int ro = (wm * 64 + i * 16 + fm) * 32 + fko;
      af[i] = *(const h8*)&As[ro];
      if constexpr (DA) af2[i] = *(const h8*)&As[4096 + ro];
    }
#pragma unroll
    for (int j = 0; j < 4; j++) {
      int co = (wn * 64 + j * 16 + fm) * 32 + fko;
      bf[j] = *(const h8*)&Bs[co];
      if constexpr (DB) bf2[j] = *(const h8*)&Bs[4096 + co];
    }
#pragma unroll
    for (int i = 0; i < 4; i++)
#pragma unroll
      for (int j = 0; j < 4; j++) {
        acc[i][j] = MFMA16(af[i], bf[j], acc[i][j]);
        if constexpr (MODE == 1) acc[i][j] = MFMA16(af2[i], bf2[j], acc[i][j]);
        if constexpr (MODE == 2) acc2[i][j] = MFMA16(af2[i], bf[j], acc2[i][j]);
      }
    __syncthreads();
  }
  const int er = (lane >> 4) * 4, ec = lane & 15;
#pragma unroll
  for (int i = 0; i < 4; i++) {
    int gr0 = m0 + wm * 64 + i * 16 + er;
#pragma unroll
    for (int j = 0; j < 4; j++) {
      int gc = n0 + wn * 64 + j * 16 + ec;
#pragma unroll
      for (int r = 0; r < 4; r++) {
        size_t off = (size_t)(gr0 + r) * ldc + coff + gc;
        if constexpr (MODE == 3) {
          ((float*)C1)[off] = acc[i][j][r] + u[gr0 + r] * wvec[gc];
        } else if constexpr (MODE == 2) {
          ((_Float16*)C1)[off] = (_Float16)acc[i][j][r];
          ((_Float16*)C2)[off] = (_Float16)acc2[i][j][r];
        } else {
          ((_Float16*)C1)[off] = (_Float16)acc[i][j][r];
        }
      }
    }
  }
}

// ---------------- MFMA modulation ----------------
// Per (l-half, vp) block: zc[vp][j*512+l] = sum_k Ac[j][k]*Bt[l][k] (K=64 stacks
// a(u) | b(u) with the v<->1023-v fold); zs likewise. Scale 1/128 in tables.
__global__ __launch_bounds__(256) void modmfma_k(
    const _Float16* __restrict__ Xh, const float* __restrict__ cj,
    const float* __restrict__ sj, _Float16* __restrict__ zc,
    _Float16* __restrict__ zs) {
  __shared__ _Float16 Bs[256 * 72];
  __shared__ _Float16 Ac[32 * 72];
  __shared__ _Float16 As[32 * 72];
  const int tid = threadIdx.x;
  const int lane = tid & 63;
  const int wid = tid >> 6;
  const int vp = blockIdx.y;
  const int l0 = blockIdx.x * 256;
  const float sc = 0.0078125f;
  {  // stage X transposed: lane -> k-row
    int r = lane;
    int u = r & 31;
    int n = (r < 32) ? ((u << 10) + vp) : ((u << 10) + 1023 - vp);
    const _Float16* src = Xh + (size_t)n * 512 + l0 + wid * 64;
#pragma unroll
    for (int i = 0; i < 8; i++) {
      h8 v = *(const h8*)(src + i * 8);
      int lb = wid * 64 + i * 8;
#pragma unroll
      for (int e = 0; e < 8; e++) Bs[(lb + e) * 72 + r] = v[e];
    }
  }
  for (int idx = tid; idx < 2048; idx += 256) {  // tables
    int kk = idx & 63, j = idx >> 6;
    int u = kk & 31;
    int n = (kk < 32) ? ((u << 10) + vp) : ((u << 10) + 1023 - vp);
    float cv = cj[(j << 15) + n] * sc;
    float sv = sj[(j << 15) + n] * sc;
    Ac[j * 72 + kk] = (_Float16)cv;
    As[j * 72 + kk] = (_Float16)((kk < 32) ? sv : -sv);
  }
  __syncthreads();
  const int fm = lane & 15, fko = (lane >> 4) * 8;
  f4 accc[2][4] = {};
  f4 accs[2][4] = {};
#pragma unroll
  for (int ks = 0; ks < 2; ks++) {
    int ko = ks * 32 + fko;
    h8 afc[2], afs[2], bf[4];
#pragma unroll
    for (int i = 0; i < 2; i++) {
      afc[i] = *(const h8*)&Ac[(i * 16 + fm) * 72 + ko];
      afs[i] = *(const h8*)&As[(i * 16 + fm) * 72 + ko];
    }
#pragma unroll
    for (int j = 0; j < 4; j++)
      bf[j] = *(const h8*)&Bs[(wid * 64 + j * 16 + fm) * 72 + ko];
#pragma unroll
    for (int i = 0; i < 2; i++)
#pragma unroll
      for (int j = 0; j < 4; j++) {
        accc[i][j] = MFMA16(afc[i], bf[j], accc[i][j]);
        accs[i][j] = MFMA16(afs[i], bf[j], accs[i][j]);
      }
  }
  const int er = (lane >> 4) * 4, ec = lane & 15;
#pragma unroll
  for (int i = 0; i < 2; i++)
#pragma unroll
    for (int j = 0; j < 4; j++)
#pragma unroll
      for (int r = 0; r < 4; r++) {
        int row = i * 16 + er + r;
        int col = l0 + wid * 64 + j * 16 + ec;
        size_t off = (size_t)vp * 16384 + row * 512 + col;
        zc[off] = (_Float16)accc[i][j][r];
        zs[off] = (_Float16)accs[i][j][r];
      }
}

// ---------------- MFMA demodulation ----------------
// Per (l-half, vp): C[m][l], m = ab*32+u: row a: sum_j cj*Pc - sj*Ps;
// row b: sum_j cj(nb)*Pc + sj(nb)*Ps. K = 2*JC stacks (Pc | Ps). + wv.cw rank-1.
template <int JC>
__global__ __launch_bounds__(256) void demodmfma_k(
    const _Float16* __restrict__ Pc, const _Float16* __restrict__ Ps,
    const float* __restrict__ cj, const float* __restrict__ sj,
    const float* __restrict__ wv, const float* __restrict__ cw,
    float* __restrict__ out, int coff) {
  constexpr int K2 = 2 * JC;
  constexpr int ST = K2 + 8;
  __shared__ _Float16 Bs[256 * ST];
  __shared__ _Float16 At[64 * ST];
  const int tid = threadIdx.x;
  const int lane = tid & 63;
  const int wid = tid >> 6;
  const int vp = blockIdx.y;
  const int l0 = blockIdx.x * 256;
  {  // stage P transposed
    constexpr int CPL = 64 / K2;  // row-groups per wave: 1 (JC=32) or 2 (JC=16)
    int r = lane & (K2 - 1);
    int chunk = wid * CPL + (CPL == 1 ? 0 : (lane >> 5));
    int lb = chunk * K2;
    const _Float16* src = (r < JC ? Pc + (size_t)vp * (JC * 512) + r * 512
                                  : Ps + (size_t)vp * (JC * 512) + (r - JC) * 512) +
                          l0 + lb;
#pragma unroll
    for (int i = 0; i < K2 / 8; i++) {
      h8 v = *(const h8*)(src + i * 8);
#pragma unroll
      for (int e = 0; e < 8; e++) Bs[(lb + i * 8 + e) * ST + r] = v[e];
    }
  }
  for (int idx = tid; idx < 64 * K2; idx += 256) {  // tables
    int kk = idx & (K2 - 1), m = idx / K2;
    int ab = m >> 5, u = m & 31;
    int n = ab ? ((u << 10) + 1023 - vp) : ((u << 10) + vp);
    float val;
    if (kk < JC) {
      val = cj[(kk << 15) + n];
    } else {
      float sv = sj[((kk - JC) << 15) + n];
      val = ab ? sv : -sv;
    }
    At[m * ST + kk] = (_Float16)val;
  }
  __syncthreads();
  const int fm = lane & 15, fko = (lane >> 4) * 8;
  f4 acc[4][4] = {};
#pragma unroll
  for (int ks = 0; ks < K2 / 32; ks++) {
    int ko = ks * 32 + fko;
    h8 af[4], bf[4];
#pragma unroll
    for (int i = 0; i < 4; i++) af[i] = *(const h8*)&At[(i * 16 + fm) * ST + ko];
#pragma unroll
    for (int j = 0; j < 4; j++) bf[j] = *(const h8*)&Bs[(wid * 64 + j * 16 + fm) * ST + ko];
#pragma unroll
    for (int i = 0; i < 4; i++)
#pragma unroll
      for (int j = 0; j < 4; j++) acc[i][j] = MFMA16(af[i], bf[j], acc[i][j]);
  }
  const int er = (lane >> 4) * 4, ec = lane & 15;
#pragma unroll
  for (int i = 0; i < 4; i++)
#pragma unroll
    for (int j = 0; j < 4; j++) {
      int col = l0 + wid * 64 + j * 16 + ec;
      float cl = cw[col];
#pragma unroll
      for (int r = 0; r < 4; r++) {
        int m = i * 16 + er + r;
        int ab = m >> 5, u = m & 31;
        int n = ab ? ((u << 10) + 1023 - vp) : ((u << 10) + vp);
        out[(size_t)n * 1536 + coff + col] = acc[i][j][r] + wv[n] * cl;
      }
    }
}

// ---------------- launch ----------------
extern "C" void kernel_launch(void* const* d_in, const int* in_sizes, int n_in,
                              void* d_out, int out_size, void* d_ws, size_t ws_size,
                              hipStream_t stream) {
  const float* X  = (const float*)d_in[0];
  const float* W1 = (const float*)d_in[1];
  const float* b1 = (const float*)d_in[2];
  const float* W2 = (const float*)d_in[3];
  const float* b2 = (const float*)d_in[4];
  const float* W3 = (const float*)d_in[5];
  const float* b3 = (const float*)d_in[6];
  float* out = (float*)d_out;
  char* w = (char*)d_ws;
  const size_t MB = 1024 * 1024;

  float* F    = (float*)(w);
  float* cj   = (float*)(w + 1 * MB);
  float* sj   = (float*)(w + 5 * MB);
  float* v1   = (float*)(w + 9 * MB);
  float* w2v  = (float*)(w + 9 * MB + 131072);
  float* w3v  = (float*)(w + 9 * MB + 262144);
  float* c1   = (float*)(w + 9 * MB + 393216);
  float* c2   = (float*)(w + 9 * MB + 395264);
  float* c3   = (float*)(w + 9 * MB + 397312);
  float* Pst  = (float*)(w + 10 * MB);             // 1 MB fp32
  _Float16* CmTh = (_Float16*)(w + 11 * MB);
  _Float16* SmTh = (_Float16*)(w + 11 * MB + 524288);
  _Float16* Cmh  = (_Float16*)(w + 12 * MB);
  _Float16* Smnh = (_Float16*)(w + 12 * MB + 524288);
  _Float16* M1T  = (_Float16*)(w + 13 * MB);
  _Float16* M2T  = (_Float16*)(w + 13 * MB + 524288);
  _Float16* M3T  = (_Float16*)(w + 14 * MB);
  float* Q       = (float*)(w + 14 * MB + 524288); // 512 KB fp32
  _Float16* Xh   = (_Float16*)(w + 16 * MB);       // 32 MB
  _Float16* zc   = (_Float16*)(w + 48 * MB);
  _Float16* zs   = (_Float16*)(w + 64 * MB);
  _Float16* Pc2h = (_Float16*)(w + 48 * MB);
  _Float16* Ps2h = (_Float16*)(w + 64 * MB);
  _Float16* Pc3h = (_Float16*)(w + 48 * MB);
  _Float16* Ps3h = (_Float16*)(w + 56 * MB);
  _Float16* zcT  = (_Float16*)(w + 80 * MB);
  _Float16* zsT  = (_Float16*)(w + 96 * MB);
  _Float16* Y2T  = (_Float16*)(w + 80 * MB);
  _Float16* Y3T  = (_Float16*)(w + 96 * MB);
  _Float16* Zh   = (_Float16*)(w + 112 * MB);
  _Float16* Y2   = (_Float16*)(w + 128 * MB);
  _Float16* Y3   = (_Float16*)(w + 144 * MB);

  // tables
  fill_F_k<<<1024, 256, 0, stream>>>(F);
  fill_CS_h_k<<<1024, 256, 0, stream>>>(Cmh, Smnh, CmTh, SmTh);
  fill_cjsj_k<<<4096, 256, 0, stream>>>(cj, sj);
  fill_vw_k<<<128, 256, 0, stream>>>(v1, w2v, w3v);
  gemv_FT_k<<<2, 256, 0, stream>>>(F, b1, c1, 512);
  gemv_FT_k<<<2, 256, 0, stream>>>(F, b2, c2, 256);
  gemv_FT_k<<<2, 256, 0, stream>>>(F, b3, c3, 128);

  // M1T = Pst^T F, Pst = W1^T F ; M2T = F1^T (W2 F1) ; M3T = F2^T (W3 F2)
  sgemm_k<<<dim3(4, 4), 256, 0, stream>>>(W1, 512, 1, F, 512, Pst, nullptr, 512, 1.f);
  sgemm_k<<<dim3(4, 4), 256, 0, stream>>>(Pst, 512, 1, F, 512, nullptr, M1T, 512, 1.f);
  sgemm_k<<<dim3(4, 2), 256, 0, stream>>>(W2, 256, 0, F, 512, Q, nullptr, 256, 1.f);
  sgemm_k<<<dim3(4, 4), 256, 0, stream>>>(F, 512, 1, Q, 512, nullptr, M2T, 256, 0.0078125f);
  sgemm_k<<<dim3(4, 1), 256, 0, stream>>>(W3, 128, 0, F, 512, Q, nullptr, 128, 1.f);
  sgemm_k<<<dim3(4, 4), 256, 0, stream>>>(F, 512, 1, Q, 512, nullptr, M3T, 128, 0.0078125f);

  // X -> fp16
  conv_xh_k<<<16384, 256, 0, stream>>>(X, Xh);

  // forward: MFMA modulate -> transpose -> dual GEMM -> fixup
  modmfma_k<<<dim3(2, 512), 256, 0, stream>>>(Xh, cj, sj, zc, zs);
  transpose_h_k<<<dim3(256, 8), 256, 0, stream>>>(zc, zcT, 512, 16384);
  transpose_h_k<<<dim3(256, 8), 256, 0, stream>>>(zs, zsT, 512, 16384);
  mfma_gemm_k<1><<<dim3(128, 4), 256, 0, stream>>>(Cmh, Smnh, zcT, zsT, Zh, nullptr,
                                                   16384, 0, nullptr, nullptr, 30, 30);
  fixup_h_k<<<1, 512, 0, stream>>>(Zh);

  // coefficient-domain L-matmuls
  mfma_gemm_k<0><<<dim3(4, 128), 256, 0, stream>>>(Zh, nullptr, M2T, nullptr, Y2, nullptr,
                                                   512, 0, nullptr, nullptr, 30, 30);
  mfma_gemm_k<0><<<dim3(4, 64), 256, 0, stream>>>(Zh, nullptr, M3T, nullptr, Y3, nullptr,
                                                  512, 0, nullptr, nullptr, 4, 5);

  // inverse branch 2
  transpose_h_k<<<dim3(256, 8), 256, 0, stream>>>(Y2, Y2T, 512, 16384);
  mfma_gemm_k<2><<<dim3(128, 4), 256, 0, stream>>>(CmTh, SmTh, Y2T, nullptr, Pc2h, Ps2h,
                                                   16384, 0, nullptr, nullptr, 30, 30);
  demodmfma_k<32><<<dim3(2, 512), 256, 0, stream>>>(Pc2h, Ps2h, cj, sj, w2v, c2, out, 512);

  // inverse branch 3
  transpose_h_k<<<dim3(128, 8), 256, 0, stream>>>(Y3, Y3T, 512, 8192);
  mfma_gemm_k<2><<<dim3(64, 4), 256, 0, stream>>>(CmTh, SmTh, Y3T, nullptr, Pc3h, Ps3h,
                                                  8192, 0, nullptr, nullptr, 30, 30);
  demodmfma_k<16><<<dim3(2, 512), 256, 0, stream>>>(Pc3h, Ps3h, cj, sj, w3v, c3, out, 1024);

  // branch 1: out1 = X M1 + v1 c1^T
  mfma_gemm_k<3><<<dim3(4, 256), 256, 0, stream>>>(Xh, nullptr, M1T, nullptr, out, nullptr,
                                                   1536, 0, v1, c1, 30, 30);
}